// Round 3
// baseline (367.183 us; speedup 1.0000x reference)
//
#include <hip/hip_runtime.h>

#define EPS 1e-6f

// Sizes (fixed): B=4, N=1024, DIM=384, H=12, d=32, BH=48
// ws layout (floats): q[48*1024*32] | k[...] | v[...] | out_pre[4096*384]

// ---------------- Kernel 1: qkv = x @ w_qkv, relu+eps on q,k, scatter to [BH][N][32] ----------------
// x: [4096][384], w: [384][1152].  BM=128, BN=128, BK=16, 256 threads, 8x8 micro-tile.
__global__ __launch_bounds__(256) void qkv_gemm(const float* __restrict__ x,
                                                const float* __restrict__ w,
                                                float* __restrict__ qw,
                                                float* __restrict__ kw,
                                                float* __restrict__ vw) {
    __shared__ float As[16][132];   // transposed A tile, padded
    __shared__ float Bs[16][128];   // natural B tile
    const int t = threadIdx.x;
    const int m0 = blockIdx.y * 128;
    const int c0 = blockIdx.x * 128;
    const int tx = t & 15, ty = t >> 4;

    float acc[8][8];
#pragma unroll
    for (int i = 0; i < 8; i++)
#pragma unroll
        for (int j = 0; j < 8; j++) acc[i][j] = 0.f;

    for (int k0 = 0; k0 < 384; k0 += 16) {
        __syncthreads();
        // A tile: 128 rows x 16 k  (512 float4)
#pragma unroll
        for (int l = 0; l < 2; l++) {
            int idx = t * 2 + l;
            int r = idx >> 2, c4 = (idx & 3) * 4;
            float4 a = *(const float4*)(x + (size_t)(m0 + r) * 384 + k0 + c4);
            As[c4 + 0][r] = a.x;
            As[c4 + 1][r] = a.y;
            As[c4 + 2][r] = a.z;
            As[c4 + 3][r] = a.w;
        }
        // B tile: 16 k x 128 cols (512 float4), natural layout
#pragma unroll
        for (int l = 0; l < 2; l++) {
            int idx = t * 2 + l;
            int kr = idx >> 5, cc = (idx & 31) * 4;
            *(float4*)&Bs[kr][cc] = *(const float4*)(w + (size_t)(k0 + kr) * 1152 + c0 + cc);
        }
        __syncthreads();
#pragma unroll
        for (int kk = 0; kk < 16; kk++) {
            float4 a0 = *(float4*)&As[kk][ty * 8];
            float4 a1 = *(float4*)&As[kk][ty * 8 + 4];
            float4 b0 = *(float4*)&Bs[kk][tx * 8];
            float4 b1 = *(float4*)&Bs[kk][tx * 8 + 4];
            float av[8] = {a0.x, a0.y, a0.z, a0.w, a1.x, a1.y, a1.z, a1.w};
            float bv[8] = {b0.x, b0.y, b0.z, b0.w, b1.x, b1.y, b1.z, b1.w};
#pragma unroll
            for (int i = 0; i < 8; i++)
#pragma unroll
                for (int j = 0; j < 8; j++) acc[i][j] += av[i] * bv[j];
        }
    }
    // epilogue: relu+eps for q,k sections; scatter to [BH][N][32]
#pragma unroll
    for (int i = 0; i < 8; i++) {
        int row = m0 + ty * 8 + i;
        int b = row >> 10, n = row & 1023;
#pragma unroll
        for (int j = 0; j < 8; j++) {
            int col = c0 + tx * 8 + j;
            float vv = acc[i][j];
            float* dst;
            int cc;
            if (col < 384) { dst = qw; cc = col; vv = fmaxf(vv, 0.f) + EPS; }
            else if (col < 768) { dst = kw; cc = col - 384; vv = fmaxf(vv, 0.f) + EPS; }
            else { dst = vw; cc = col - 768; }
            int h = cc >> 5, dd = cc & 31;
            dst[(size_t)((b * 12 + h) * 1024 + n) * 32 + dd] = vv;
        }
    }
}

// ---------------- Kernel 2: Toeplitz-masked linear attention ----------------
// q,k,v: [48][1024][32]; tw: [2047]; op: [4096][384]
// Block: one (bh, 64-row tile). 256 threads. S-phase 16x16 grid of 4x4 micro;
// PV-phase: thread t owns row t>>2, cols (t&3)*8..+7.  num/den accumulate in f64
// (den has catastrophic cancellation; np reference FFT path is f64).
__global__ __launch_bounds__(256) void toep_attn(const float* __restrict__ q,
                                                 const float* __restrict__ k,
                                                 const float* __restrict__ v,
                                                 const float* __restrict__ tw,
                                                 float* __restrict__ op) {
    const int t = threadIdx.x;
    const int n0 = blockIdx.x * 64;
    const int bh = blockIdx.y;
    const int b = bh / 12, h = bh % 12;
    __shared__ float Qt[32][68];   // transposed, padded
    __shared__ float Kt[32][68];
    __shared__ float Vs[64][32];   // natural (broadcast reads)
    __shared__ float Ss[64][68];   // padded
    __shared__ float Ts[128];

    const float* qb = q + (size_t)bh * 1024 * 32;
    const float* kb = k + (size_t)bh * 1024 * 32;
    const float* vb = v + (size_t)bh * 1024 * 32;

    // stage Q transposed (once)
#pragma unroll
    for (int l = 0; l < 2; l++) {
        int idx = t * 2 + l;                 // [0,512)
        int r = idx >> 3, c4 = (idx & 7) * 4;
        float4 a = *(const float4*)(qb + (size_t)(n0 + r) * 32 + c4);
        Qt[c4 + 0][r] = a.x;
        Qt[c4 + 1][r] = a.y;
        Qt[c4 + 2][r] = a.z;
        Qt[c4 + 3][r] = a.w;
    }

    const int sx = t & 15, sy = t >> 4;
    const int pr = t >> 2;
    const int pc = (t & 3) * 8;
    double num[8] = {0, 0, 0, 0, 0, 0, 0, 0};
    double den = 0.0;

    for (int m0 = 0; m0 < 1024; m0 += 64) {
        __syncthreads();   // previous PV done before overwriting Kt/Vs
#pragma unroll
        for (int l = 0; l < 2; l++) {
            int idx = t * 2 + l;
            int r = idx >> 3, c4 = (idx & 7) * 4;
            float4 a = *(const float4*)(kb + (size_t)(m0 + r) * 32 + c4);
            Kt[c4 + 0][r] = a.x;
            Kt[c4 + 1][r] = a.y;
            Kt[c4 + 2][r] = a.z;
            Kt[c4 + 3][r] = a.w;
            ((float4*)&Vs[0][0])[idx] = *(const float4*)(vb + (size_t)m0 * 32 + idx * 4);
        }
        // Toeplitz window: index (n0+r)-(m0+m)+1023 = n0-m0+960 + (r-m+63); always in [0,2046]
        if (t < 127) Ts[t] = tw[n0 - m0 + 960 + t];
        __syncthreads();

        // S = (Q K^T) * T   (64x64 tile)
        float acc[4][4];
#pragma unroll
        for (int i = 0; i < 4; i++)
#pragma unroll
            for (int j = 0; j < 4; j++) acc[i][j] = 0.f;
#pragma unroll
        for (int kk = 0; kk < 32; kk++) {
            float4 a = *(float4*)&Qt[kk][sy * 4];
            float4 bb = *(float4*)&Kt[kk][sx * 4];
            float av[4] = {a.x, a.y, a.z, a.w};
            float bv[4] = {bb.x, bb.y, bb.z, bb.w};
#pragma unroll
            for (int i = 0; i < 4; i++)
#pragma unroll
                for (int j = 0; j < 4; j++) acc[i][j] += av[i] * bv[j];
        }
#pragma unroll
        for (int i = 0; i < 4; i++) {
            int r = sy * 4 + i;
            float4 srow;
            srow.x = acc[i][0] * Ts[r - sx * 4 + 63];
            srow.y = acc[i][1] * Ts[r - sx * 4 + 62];
            srow.z = acc[i][2] * Ts[r - sx * 4 + 61];
            srow.w = acc[i][3] * Ts[r - sx * 4 + 60];
            *(float4*)&Ss[r][sx * 4] = srow;
        }
        __syncthreads();

        // PV: num += S·V ; den += S·1   (f64 accumulation — cancellation-safe)
#pragma unroll 4
        for (int m = 0; m < 64; m++) {
            double s = (double)Ss[pr][m];
            float4 v0 = *(float4*)&Vs[m][pc];
            float4 v1 = *(float4*)&Vs[m][pc + 4];
            den += s;
            num[0] += s * (double)v0.x; num[1] += s * (double)v0.y;
            num[2] += s * (double)v0.z; num[3] += s * (double)v0.w;
            num[4] += s * (double)v1.x; num[5] += s * (double)v1.y;
            num[6] += s * (double)v1.z; num[7] += s * (double)v1.w;
        }
    }
    double inv = 1.0 / (den + (double)EPS);
    float* o = op + (size_t)((b * 1024) + n0 + pr) * 384 + h * 32 + pc;
    float4 o0 = {(float)(num[0] * inv), (float)(num[1] * inv),
                 (float)(num[2] * inv), (float)(num[3] * inv)};
    float4 o1 = {(float)(num[4] * inv), (float)(num[5] * inv),
                 (float)(num[6] * inv), (float)(num[7] * inv)};
    *(float4*)o = o0;
    *(float4*)(o + 4) = o1;
}

// ---------------- Kernel 3: out = op @ w_out^T + b_out ----------------
// op: [4096][384], w_out: [384][384], b_out: [384]
__global__ __launch_bounds__(256) void out_gemm(const float* __restrict__ a,
                                                const float* __restrict__ w,
                                                const float* __restrict__ bias,
                                                float* __restrict__ out) {
    __shared__ float As[16][132];
    __shared__ float Bs[16][132];   // Bs[kk][cout] = w[cout][kk] (transposed), padded
    const int t = threadIdx.x;
    const int m0 = blockIdx.y * 128;
    const int c0 = blockIdx.x * 128;
    const int tx = t & 15, ty = t >> 4;

    float acc[8][8];
#pragma unroll
    for (int i = 0; i < 8; i++)
#pragma unroll
        for (int j = 0; j < 8; j++) acc[i][j] = 0.f;

    for (int k0 = 0; k0 < 384; k0 += 16) {
        __syncthreads();
#pragma unroll
        for (int l = 0; l < 2; l++) {
            int idx = t * 2 + l;
            int r = idx >> 2, c4 = (idx & 3) * 4;
            float4 av = *(const float4*)(a + (size_t)(m0 + r) * 384 + k0 + c4);
            As[c4 + 0][r] = av.x;
            As[c4 + 1][r] = av.y;
            As[c4 + 2][r] = av.z;
            As[c4 + 3][r] = av.w;
        }
#pragma unroll
        for (int l = 0; l < 2; l++) {
            int idx = t * 2 + l;
            int r = idx >> 2, c4 = (idx & 3) * 4;   // r = cout offset, c4 = k offset
            float4 wv = *(const float4*)(w + (size_t)(c0 + r) * 384 + k0 + c4);
            Bs[c4 + 0][r] = wv.x;
            Bs[c4 + 1][r] = wv.y;
            Bs[c4 + 2][r] = wv.z;
            Bs[c4 + 3][r] = wv.w;
        }
        __syncthreads();
#pragma unroll
        for (int kk = 0; kk < 16; kk++) {
            float4 a0 = *(float4*)&As[kk][ty * 8];
            float4 a1 = *(float4*)&As[kk][ty * 8 + 4];
            float4 b0 = *(float4*)&Bs[kk][tx * 8];
            float4 b1 = *(float4*)&Bs[kk][tx * 8 + 4];
            float av[8] = {a0.x, a0.y, a0.z, a0.w, a1.x, a1.y, a1.z, a1.w};
            float bv[8] = {b0.x, b0.y, b0.z, b0.w, b1.x, b1.y, b1.z, b1.w};
#pragma unroll
            for (int i = 0; i < 8; i++)
#pragma unroll
                for (int j = 0; j < 8; j++) acc[i][j] += av[i] * bv[j];
        }
    }
#pragma unroll
    for (int i = 0; i < 8; i++) {
        int row = m0 + ty * 8 + i;
#pragma unroll
        for (int j = 0; j < 8; j++) {
            int col = c0 + tx * 8 + j;
            out[(size_t)row * 384 + col] = acc[i][j] + bias[col];
        }
    }
}

extern "C" void kernel_launch(void* const* d_in, const int* in_sizes, int n_in,
                              void* d_out, int out_size, void* d_ws, size_t ws_size,
                              hipStream_t stream) {
    const float* x     = (const float*)d_in[0];
    const float* w_qkv = (const float*)d_in[1];
    const float* w_out = (const float*)d_in[2];
    const float* b_out = (const float*)d_in[3];
    const float* tw    = (const float*)d_in[4];
    float* out = (float*)d_out;

    float* qw = (float*)d_ws;            // 48*1024*32 = 1572864 floats
    float* kw = qw + 1572864;
    float* vw = kw + 1572864;
    float* op = vw + 1572864;            // 4096*384  = 1572864 floats

    qkv_gemm<<<dim3(9, 32), 256, 0, stream>>>(x, w_qkv, qw, kw, vw);
    toep_attn<<<dim3(16, 48), 256, 0, stream>>>(qw, kw, vw, tw, op);
    out_gemm<<<dim3(3, 32), 256, 0, stream>>>(op, w_out, b_out, out);
}

// Round 4
// 323.013 us; speedup vs baseline: 1.1367x; 1.1367x over previous
//
#include <hip/hip_runtime.h>

#define EPS 1e-6f

// Sizes (fixed): B=4, N=1024, DIM=384, H=12, d=32, BH=48
// ws layout (floats): q[48*1024*32] | k[...] | v[...] | out_pre[4096*384]

// ---------------- Kernel 1: qkv = x @ w_qkv, relu+eps on q,k, scatter to [BH][N][32] ----------------
// x: [4096][384], w: [384][1152].  BM=64, BN=64, BK=32, 256 threads, 4x4 micro-tile.
// Grid (18, 64) = 1152 blocks (was 288 at 128x128 -> CUs starved).
__global__ __launch_bounds__(256) void qkv_gemm(const float* __restrict__ x,
                                                const float* __restrict__ w,
                                                float* __restrict__ qw,
                                                float* __restrict__ kw,
                                                float* __restrict__ vw) {
    __shared__ float As[32][68];   // transposed A tile: As[k][row]
    __shared__ float Bs[32][68];   // natural B tile:    Bs[k][col]
    const int t = threadIdx.x;
    const int m0 = blockIdx.y * 64;
    const int c0 = blockIdx.x * 64;
    const int tx = t & 15, ty = t >> 4;

    float acc[4][4];
#pragma unroll
    for (int i = 0; i < 4; i++)
#pragma unroll
        for (int j = 0; j < 4; j++) acc[i][j] = 0.f;

    for (int k0 = 0; k0 < 384; k0 += 32) {
        __syncthreads();
        // A tile: 64 rows x 32 k (512 float4), store transposed
#pragma unroll
        for (int l = 0; l < 2; l++) {
            int idx = t * 2 + l;
            int r = idx >> 3, c4 = (idx & 7) * 4;
            float4 a = *(const float4*)(x + (size_t)(m0 + r) * 384 + k0 + c4);
            As[c4 + 0][r] = a.x;
            As[c4 + 1][r] = a.y;
            As[c4 + 2][r] = a.z;
            As[c4 + 3][r] = a.w;
        }
        // B tile: 32 k x 64 cols (512 float4), natural
#pragma unroll
        for (int l = 0; l < 2; l++) {
            int idx = t * 2 + l;
            int kr = idx >> 4, cc = (idx & 15) * 4;
            *(float4*)&Bs[kr][cc] = *(const float4*)(w + (size_t)(k0 + kr) * 1152 + c0 + cc);
        }
        __syncthreads();
#pragma unroll
        for (int kk = 0; kk < 32; kk++) {
            float4 a = *(float4*)&As[kk][ty * 4];
            float4 bb = *(float4*)&Bs[kk][tx * 4];
            float av[4] = {a.x, a.y, a.z, a.w};
            float bv[4] = {bb.x, bb.y, bb.z, bb.w};
#pragma unroll
            for (int i = 0; i < 4; i++)
#pragma unroll
                for (int j = 0; j < 4; j++) acc[i][j] += av[i] * bv[j];
        }
    }
    // epilogue: relu+eps for q,k sections; scatter to [BH][N][32]
    // c0 is a multiple of 64; 384 % 64 == 0 so the whole block is in one section.
    const int sec = (c0 + tx * 4) / 384;           // 0=q, 1=k, 2=v (uniform per block)
    float* dst = (sec == 0) ? qw : (sec == 1) ? kw : vw;
    const int cc0 = c0 + tx * 4 - sec * 384;
    const int h = cc0 >> 5, dd = cc0 & 31;
#pragma unroll
    for (int i = 0; i < 4; i++) {
        int row = m0 + ty * 4 + i;
        int b = row >> 10, n = row & 1023;
        float4 o;
        if (sec < 2) {
            o.x = fmaxf(acc[i][0], 0.f) + EPS;
            o.y = fmaxf(acc[i][1], 0.f) + EPS;
            o.z = fmaxf(acc[i][2], 0.f) + EPS;
            o.w = fmaxf(acc[i][3], 0.f) + EPS;
        } else {
            o = make_float4(acc[i][0], acc[i][1], acc[i][2], acc[i][3]);
        }
        *(float4*)(dst + (size_t)((b * 12 + h) * 1024 + n) * 32 + dd) = o;
    }
}

// ---------------- Kernel 2: Toeplitz-masked linear attention ----------------
// q,k,v: [48][1024][32]; tw: [2047]; op: [4096][384]
// One block per (bh, 64-row tile); 256 threads; num/den accumulate in f64
// (den has catastrophic cancellation; np reference FFT path is f64).
// V staged in LDS as f64 (converted once -> kills 8 cvt_f64_f32 per m per thread).
// K/V global loads for tile t+1 issued before S-phase of tile t (pipelined).
__global__ __launch_bounds__(256) void toep_attn(const float* __restrict__ q,
                                                 const float* __restrict__ k,
                                                 const float* __restrict__ v,
                                                 const float* __restrict__ tw,
                                                 float* __restrict__ op) {
    const int t = threadIdx.x;
    const int n0 = blockIdx.x * 64;
    const int bh = blockIdx.y;
    const int b = bh / 12, h = bh % 12;
    __shared__ float Qt[32][68];    // transposed, padded
    __shared__ float Kt[32][68];
    __shared__ double Vd[64][32];   // f64 V tile (exact converts)
    __shared__ float Ss[64][68];    // padded
    __shared__ float Ts[128];

    const float* qb = q + (size_t)bh * 32768;
    const float* kb = k + (size_t)bh * 32768;
    const float* vb = v + (size_t)bh * 32768;

    // stage Q transposed (once)
#pragma unroll
    for (int l = 0; l < 2; l++) {
        int idx = t * 2 + l;
        int r = idx >> 3, c4 = (idx & 7) * 4;
        float4 a = *(const float4*)(qb + (size_t)(n0 + r) * 32 + c4);
        Qt[c4 + 0][r] = a.x;
        Qt[c4 + 1][r] = a.y;
        Qt[c4 + 2][r] = a.z;
        Qt[c4 + 3][r] = a.w;
    }

    float4 kreg[2], vreg[2];
    // prologue: load + stage tile 0
#pragma unroll
    for (int l = 0; l < 2; l++) {
        int idx = t * 2 + l;
        int r = idx >> 3, c4 = (idx & 7) * 4;
        kreg[l] = *(const float4*)(kb + (size_t)r * 32 + c4);
        vreg[l] = *(const float4*)(vb + idx * 4);
    }
#pragma unroll
    for (int l = 0; l < 2; l++) {
        int idx = t * 2 + l;
        int r = idx >> 3, c4 = (idx & 7) * 4;
        Kt[c4 + 0][r] = kreg[l].x;
        Kt[c4 + 1][r] = kreg[l].y;
        Kt[c4 + 2][r] = kreg[l].z;
        Kt[c4 + 3][r] = kreg[l].w;
        double2 d0 = {(double)vreg[l].x, (double)vreg[l].y};
        double2 d1 = {(double)vreg[l].z, (double)vreg[l].w};
        *(double2*)&Vd[r][c4] = d0;
        *(double2*)&Vd[r][c4 + 2] = d1;
    }
    if (t < 127) Ts[t] = tw[n0 + 960 + t];
    __syncthreads();

    const int sx = t & 15, sy = t >> 4;
    const int pr = t >> 2;
    const int pc = (t & 3) * 8;
    double num[8] = {0, 0, 0, 0, 0, 0, 0, 0};
    double den = 0.0;

    for (int tt = 0; tt < 16; tt++) {
        const int m0 = tt * 64;
        // issue next tile's K/V loads (latency hides under S + PV)
        if (tt < 15) {
#pragma unroll
            for (int l = 0; l < 2; l++) {
                int idx = t * 2 + l;
                int r = idx >> 3, c4 = (idx & 7) * 4;
                kreg[l] = *(const float4*)(kb + (size_t)(m0 + 64 + r) * 32 + c4);
                vreg[l] = *(const float4*)(vb + (size_t)(m0 + 64) * 32 + idx * 4);
            }
        }

        // S = (Q K^T) * T   (64x64 tile)
        float acc[4][4];
#pragma unroll
        for (int i = 0; i < 4; i++)
#pragma unroll
            for (int j = 0; j < 4; j++) acc[i][j] = 0.f;
#pragma unroll
        for (int kk = 0; kk < 32; kk++) {
            float4 a = *(float4*)&Qt[kk][sy * 4];
            float4 bb = *(float4*)&Kt[kk][sx * 4];
            float av[4] = {a.x, a.y, a.z, a.w};
            float bv[4] = {bb.x, bb.y, bb.z, bb.w};
#pragma unroll
            for (int i = 0; i < 4; i++)
#pragma unroll
                for (int j = 0; j < 4; j++) acc[i][j] += av[i] * bv[j];
        }
#pragma unroll
        for (int i = 0; i < 4; i++) {
            int r = sy * 4 + i;
            float4 srow;
            srow.x = acc[i][0] * Ts[r - sx * 4 + 63];
            srow.y = acc[i][1] * Ts[r - sx * 4 + 62];
            srow.z = acc[i][2] * Ts[r - sx * 4 + 61];
            srow.w = acc[i][3] * Ts[r - sx * 4 + 60];
            *(float4*)&Ss[r][sx * 4] = srow;
        }
        __syncthreads();   // b1: Ss ready; S-phase done -> Kt is dead, can overwrite

        if (tt < 15) {
#pragma unroll
            for (int l = 0; l < 2; l++) {
                int idx = t * 2 + l;
                int r = idx >> 3, c4 = (idx & 7) * 4;
                Kt[c4 + 0][r] = kreg[l].x;
                Kt[c4 + 1][r] = kreg[l].y;
                Kt[c4 + 2][r] = kreg[l].z;
                Kt[c4 + 3][r] = kreg[l].w;
            }
            if (t < 127) Ts[t] = tw[n0 - (m0 + 64) + 960 + t];
        }

        // PV: num += S·V ; den += S·1   (f64, exact products; V already f64 in LDS)
#pragma unroll 4
        for (int m = 0; m < 64; m++) {
            double s = (double)Ss[pr][m];
            double2 va = *(double2*)&Vd[m][pc];
            double2 vb2 = *(double2*)&Vd[m][pc + 2];
            double2 vc = *(double2*)&Vd[m][pc + 4];
            double2 vd2 = *(double2*)&Vd[m][pc + 6];
            den += s;
            num[0] += s * va.x;  num[1] += s * va.y;
            num[2] += s * vb2.x; num[3] += s * vb2.y;
            num[4] += s * vc.x;  num[5] += s * vc.y;
            num[6] += s * vd2.x; num[7] += s * vd2.y;
        }
        __syncthreads();   // b2: PV done -> Vd free; Kt/Ts writes visible for next S
        if (tt < 15) {
#pragma unroll
            for (int l = 0; l < 2; l++) {
                int idx = t * 2 + l;
                int r = idx >> 3, c4 = (idx & 7) * 4;
                double2 d0 = {(double)vreg[l].x, (double)vreg[l].y};
                double2 d1 = {(double)vreg[l].z, (double)vreg[l].w};
                *(double2*)&Vd[r][c4] = d0;
                *(double2*)&Vd[r][c4 + 2] = d1;
            }
        }
    }
    double inv = 1.0 / (den + (double)EPS);
    float* o = op + (size_t)((b * 1024) + n0 + pr) * 384 + h * 32 + pc;
    float4 o0 = {(float)(num[0] * inv), (float)(num[1] * inv),
                 (float)(num[2] * inv), (float)(num[3] * inv)};
    float4 o1 = {(float)(num[4] * inv), (float)(num[5] * inv),
                 (float)(num[6] * inv), (float)(num[7] * inv)};
    *(float4*)o = o0;
    *(float4*)(o + 4) = o1;
}

// ---------------- Kernel 3: out = op @ w_out^T + b_out ----------------
// op: [4096][384], w_out: [384][384], b_out: [384]. BM=BN=64, BK=32.
// Grid (6, 64) = 384 blocks (was 96 -> 2/3 of the GPU idle).
__global__ __launch_bounds__(256) void out_gemm(const float* __restrict__ a,
                                                const float* __restrict__ w,
                                                const float* __restrict__ bias,
                                                float* __restrict__ out) {
    __shared__ float As[32][68];   // As[k][row]
    __shared__ float Bs[32][68];   // Bs[k][cout] = w[cout][k] transposed
    const int t = threadIdx.x;
    const int m0 = blockIdx.y * 64;
    const int c0 = blockIdx.x * 64;
    const int tx = t & 15, ty = t >> 4;

    float acc[4][4];
#pragma unroll
    for (int i = 0; i < 4; i++)
#pragma unroll
        for (int j = 0; j < 4; j++) acc[i][j] = 0.f;

    for (int k0 = 0; k0 < 384; k0 += 32) {
        __syncthreads();
#pragma unroll
        for (int l = 0; l < 2; l++) {
            int idx = t * 2 + l;
            int r = idx >> 3, c4 = (idx & 7) * 4;
            float4 av = *(const float4*)(a + (size_t)(m0 + r) * 384 + k0 + c4);
            As[c4 + 0][r] = av.x;
            As[c4 + 1][r] = av.y;
            As[c4 + 2][r] = av.z;
            As[c4 + 3][r] = av.w;
        }
#pragma unroll
        for (int l = 0; l < 2; l++) {
            int idx = t * 2 + l;
            int r = idx >> 3, c4 = (idx & 7) * 4;   // r = cout offset, c4 = k offset
            float4 wv = *(const float4*)(w + (size_t)(c0 + r) * 384 + k0 + c4);
            Bs[c4 + 0][r] = wv.x;
            Bs[c4 + 1][r] = wv.y;
            Bs[c4 + 2][r] = wv.z;
            Bs[c4 + 3][r] = wv.w;
        }
        __syncthreads();
#pragma unroll
        for (int kk = 0; kk < 32; kk++) {
            float4 a4 = *(float4*)&As[kk][ty * 4];
            float4 b4 = *(float4*)&Bs[kk][tx * 4];
            float av[4] = {a4.x, a4.y, a4.z, a4.w};
            float bv[4] = {b4.x, b4.y, b4.z, b4.w};
#pragma unroll
            for (int i = 0; i < 4; i++)
#pragma unroll
                for (int j = 0; j < 4; j++) acc[i][j] += av[i] * bv[j];
        }
    }
    const int col = c0 + tx * 4;
    float4 bb = *(const float4*)(bias + col);
#pragma unroll
    for (int i = 0; i < 4; i++) {
        int row = m0 + ty * 4 + i;
        float4 o = {acc[i][0] + bb.x, acc[i][1] + bb.y,
                    acc[i][2] + bb.z, acc[i][3] + bb.w};
        *(float4*)(out + (size_t)row * 384 + col) = o;
    }
}

extern "C" void kernel_launch(void* const* d_in, const int* in_sizes, int n_in,
                              void* d_out, int out_size, void* d_ws, size_t ws_size,
                              hipStream_t stream) {
    const float* x     = (const float*)d_in[0];
    const float* w_qkv = (const float*)d_in[1];
    const float* w_out = (const float*)d_in[2];
    const float* b_out = (const float*)d_in[3];
    const float* tw    = (const float*)d_in[4];
    float* out = (float*)d_out;

    float* qw = (float*)d_ws;            // 48*1024*32 = 1572864 floats
    float* kw = qw + 1572864;
    float* vw = kw + 1572864;
    float* op = vw + 1572864;            // 4096*384  = 1572864 floats

    qkv_gemm<<<dim3(18, 64), 256, 0, stream>>>(x, w_qkv, qw, kw, vw);
    toep_attn<<<dim3(16, 48), 256, 0, stream>>>(qw, kw, vw, tw, op);
    out_gemm<<<dim3(6, 64), 256, 0, stream>>>(op, w_out, b_out, out);
}

// Round 6
// 313.698 us; speedup vs baseline: 1.1705x; 1.0297x over previous
//
#include <hip/hip_runtime.h>

#define EPS 1e-6f

// Sizes (fixed): B=4, N=1024, DIM=384, H=12, d=32, BH=48
// ws layout (floats): q[48*1024*32] | k[...] | v[...] | out_pre[4096*384]

// ---------------- Kernel 1: qkv = x @ w_qkv, relu+eps on q,k, scatter to [BH][N][32] ----------------
__global__ __launch_bounds__(256) void qkv_gemm(const float* __restrict__ x,
                                                const float* __restrict__ w,
                                                float* __restrict__ qw,
                                                float* __restrict__ kw,
                                                float* __restrict__ vw) {
    __shared__ float As[32][68];   // transposed A tile: As[k][row]
    __shared__ float Bs[32][68];   // natural B tile:    Bs[k][col]
    const int t = threadIdx.x;
    const int m0 = blockIdx.y * 64;
    const int c0 = blockIdx.x * 64;
    const int tx = t & 15, ty = t >> 4;

    float acc[4][4];
#pragma unroll
    for (int i = 0; i < 4; i++)
#pragma unroll
        for (int j = 0; j < 4; j++) acc[i][j] = 0.f;

    for (int k0 = 0; k0 < 384; k0 += 32) {
        __syncthreads();
#pragma unroll
        for (int l = 0; l < 2; l++) {
            int idx = t * 2 + l;
            int r = idx >> 3, c4 = (idx & 7) * 4;
            float4 a = *(const float4*)(x + (size_t)(m0 + r) * 384 + k0 + c4);
            As[c4 + 0][r] = a.x;
            As[c4 + 1][r] = a.y;
            As[c4 + 2][r] = a.z;
            As[c4 + 3][r] = a.w;
        }
#pragma unroll
        for (int l = 0; l < 2; l++) {
            int idx = t * 2 + l;
            int kr = idx >> 4, cc = (idx & 15) * 4;
            *(float4*)&Bs[kr][cc] = *(const float4*)(w + (size_t)(k0 + kr) * 1152 + c0 + cc);
        }
        __syncthreads();
#pragma unroll
        for (int kk = 0; kk < 32; kk++) {
            float4 a = *(float4*)&As[kk][ty * 4];
            float4 bb = *(float4*)&Bs[kk][tx * 4];
            float av[4] = {a.x, a.y, a.z, a.w};
            float bv[4] = {bb.x, bb.y, bb.z, bb.w};
#pragma unroll
            for (int i = 0; i < 4; i++)
#pragma unroll
                for (int j = 0; j < 4; j++) acc[i][j] += av[i] * bv[j];
        }
    }
    const int sec = (c0 + tx * 4) / 384;           // 0=q, 1=k, 2=v (uniform per block)
    float* dst = (sec == 0) ? qw : (sec == 1) ? kw : vw;
    const int cc0 = c0 + tx * 4 - sec * 384;
    const int h = cc0 >> 5, dd = cc0 & 31;
#pragma unroll
    for (int i = 0; i < 4; i++) {
        int row = m0 + ty * 4 + i;
        int b = row >> 10, n = row & 1023;
        float4 o;
        if (sec < 2) {
            o.x = fmaxf(acc[i][0], 0.f) + EPS;
            o.y = fmaxf(acc[i][1], 0.f) + EPS;
            o.z = fmaxf(acc[i][2], 0.f) + EPS;
            o.w = fmaxf(acc[i][3], 0.f) + EPS;
        } else {
            o = make_float4(acc[i][0], acc[i][1], acc[i][2], acc[i][3]);
        }
        *(float4*)(dst + (size_t)((b * 12 + h) * 1024 + n) * 32 + dd) = o;
    }
}

// ---------------- Kernel 2: Toeplitz-masked linear attention ----------------
// q,k,v: [48][1024][32]; tw: [2047]; op: [4096][384]
// R3-identical numerics (f32 S, f64 num/den accumulation in m-order 0..1023).
// V staged in LDS as f64 with stride 34 doubles (272B): ds_write banks spread
// (R4's [64][32] stride 256B was a 16-way write conflict - banks {0,16} only);
// PV V-reads are same-address broadcasts (uniform row m) -> conflict-free.
// K/V global loads for tile t+1 issued before S-phase of tile t (pipelined).
__global__ __launch_bounds__(256) void toep_attn(const float* __restrict__ q,
                                                 const float* __restrict__ k,
                                                 const float* __restrict__ v,
                                                 const float* __restrict__ tw,
                                                 float* __restrict__ op) {
    const int t = threadIdx.x;
    const int n0 = blockIdx.x * 64;
    const int bh = blockIdx.y;
    const int b = bh / 12, h = bh % 12;
    __shared__ float Qt[32][68];    // transposed, padded
    __shared__ float Kt[32][68];
    __shared__ double Vd[64][34];   // f64 V tile, stride 272B (write-bank-clean, 16B-aligned)
    __shared__ float Ss[64][68];    // padded
    __shared__ float Ts[128];

    const float* qb = q + (size_t)bh * 32768;
    const float* kb = k + (size_t)bh * 32768;
    const float* vb = v + (size_t)bh * 32768;

    // stage Q transposed (once)
#pragma unroll
    for (int l = 0; l < 2; l++) {
        int idx = t * 2 + l;
        int r = idx >> 3, c4 = (idx & 7) * 4;
        float4 a = *(const float4*)(qb + (size_t)(n0 + r) * 32 + c4);
        Qt[c4 + 0][r] = a.x;
        Qt[c4 + 1][r] = a.y;
        Qt[c4 + 2][r] = a.z;
        Qt[c4 + 3][r] = a.w;
    }

    float4 kreg[2], vreg[2];
    // prologue: load + stage tile 0
#pragma unroll
    for (int l = 0; l < 2; l++) {
        int idx = t * 2 + l;
        int r = idx >> 3, c4 = (idx & 7) * 4;
        kreg[l] = *(const float4*)(kb + (size_t)r * 32 + c4);
        vreg[l] = *(const float4*)(vb + idx * 4);
    }
#pragma unroll
    for (int l = 0; l < 2; l++) {
        int idx = t * 2 + l;
        int r = idx >> 3, c4 = (idx & 7) * 4;
        Kt[c4 + 0][r] = kreg[l].x;
        Kt[c4 + 1][r] = kreg[l].y;
        Kt[c4 + 2][r] = kreg[l].z;
        Kt[c4 + 3][r] = kreg[l].w;
        double2 d0 = {(double)vreg[l].x, (double)vreg[l].y};
        double2 d1 = {(double)vreg[l].z, (double)vreg[l].w};
        *(double2*)&Vd[r][c4] = d0;
        *(double2*)&Vd[r][c4 + 2] = d1;
    }
    if (t < 127) Ts[t] = tw[n0 + 960 + t];
    __syncthreads();

    const int sx = t & 15, sy = t >> 4;
    const int pr = t >> 2;
    const int pc = (t & 3) * 8;
    double num[8] = {0, 0, 0, 0, 0, 0, 0, 0};
    double den = 0.0;

    for (int tt = 0; tt < 16; tt++) {
        const int m0 = tt * 64;
        // issue next tile's K/V loads (latency hides under S + PV)
        if (tt < 15) {
#pragma unroll
            for (int l = 0; l < 2; l++) {
                int idx = t * 2 + l;
                int r = idx >> 3, c4 = (idx & 7) * 4;
                kreg[l] = *(const float4*)(kb + (size_t)(m0 + 64 + r) * 32 + c4);
                vreg[l] = *(const float4*)(vb + (size_t)(m0 + 64) * 32 + idx * 4);
            }
        }

        // S = (Q K^T) * T   (64x64 tile, f32 - identical to R3)
        float acc[4][4];
#pragma unroll
        for (int i = 0; i < 4; i++)
#pragma unroll
            for (int j = 0; j < 4; j++) acc[i][j] = 0.f;
#pragma unroll
        for (int kk = 0; kk < 32; kk++) {
            float4 a = *(float4*)&Qt[kk][sy * 4];
            float4 bb = *(float4*)&Kt[kk][sx * 4];
            float av[4] = {a.x, a.y, a.z, a.w};
            float bv[4] = {bb.x, bb.y, bb.z, bb.w};
#pragma unroll
            for (int i = 0; i < 4; i++)
#pragma unroll
                for (int j = 0; j < 4; j++) acc[i][j] += av[i] * bv[j];
        }
#pragma unroll
        for (int i = 0; i < 4; i++) {
            int r = sy * 4 + i;
            float4 srow;
            srow.x = acc[i][0] * Ts[r - sx * 4 + 63];
            srow.y = acc[i][1] * Ts[r - sx * 4 + 62];
            srow.z = acc[i][2] * Ts[r - sx * 4 + 61];
            srow.w = acc[i][3] * Ts[r - sx * 4 + 60];
            *(float4*)&Ss[r][sx * 4] = srow;
        }
        __syncthreads();   // b1: Ss ready; S-phase done -> Kt/Ts dead, can overwrite

        if (tt < 15) {
#pragma unroll
            for (int l = 0; l < 2; l++) {
                int idx = t * 2 + l;
                int r = idx >> 3, c4 = (idx & 7) * 4;
                Kt[c4 + 0][r] = kreg[l].x;
                Kt[c4 + 1][r] = kreg[l].y;
                Kt[c4 + 2][r] = kreg[l].z;
                Kt[c4 + 3][r] = kreg[l].w;
            }
            if (t < 127) Ts[t] = tw[n0 - (m0 + 64) + 960 + t];
        }

        // PV: num += S.V ; den += S.1   (f64 accumulation; V already f64 in LDS;
        // only 1 cvt per m per thread - the S value)
#pragma unroll 4
        for (int m = 0; m < 64; m++) {
            double s = (double)Ss[pr][m];
            double2 va  = *(double2*)&Vd[m][pc];
            double2 vb2 = *(double2*)&Vd[m][pc + 2];
            double2 vc  = *(double2*)&Vd[m][pc + 4];
            double2 vd2 = *(double2*)&Vd[m][pc + 6];
            den += s;
            num[0] += s * va.x;  num[1] += s * va.y;
            num[2] += s * vb2.x; num[3] += s * vb2.y;
            num[4] += s * vc.x;  num[5] += s * vc.y;
            num[6] += s * vd2.x; num[7] += s * vd2.y;
        }
        __syncthreads();   // b2: PV done -> Vd free; Kt/Ts writes visible for next S
        if (tt < 15) {
#pragma unroll
            for (int l = 0; l < 2; l++) {
                int idx = t * 2 + l;
                int r = idx >> 3, c4 = (idx & 7) * 4;
                double2 d0 = {(double)vreg[l].x, (double)vreg[l].y};
                double2 d1 = {(double)vreg[l].z, (double)vreg[l].w};
                *(double2*)&Vd[r][c4] = d0;
                *(double2*)&Vd[r][c4 + 2] = d1;
            }
        }
    }
    double inv = 1.0 / (den + (double)EPS);
    float* o = op + (size_t)((b * 1024) + n0 + pr) * 384 + h * 32 + pc;
    float4 o0 = {(float)(num[0] * inv), (float)(num[1] * inv),
                 (float)(num[2] * inv), (float)(num[3] * inv)};
    float4 o1 = {(float)(num[4] * inv), (float)(num[5] * inv),
                 (float)(num[6] * inv), (float)(num[7] * inv)};
    *(float4*)o = o0;
    *(float4*)(o + 4) = o1;
}

// ---------------- Kernel 3: out = op @ w_out^T + b_out ----------------
__global__ __launch_bounds__(256) void out_gemm(const float* __restrict__ a,
                                                const float* __restrict__ w,
                                                const float* __restrict__ bias,
                                                float* __restrict__ out) {
    __shared__ float As[32][68];   // As[k][row]
    __shared__ float Bs[32][68];   // Bs[k][cout] = w[cout][k] transposed
    const int t = threadIdx.x;
    const int m0 = blockIdx.y * 64;
    const int c0 = blockIdx.x * 64;
    const int tx = t & 15, ty = t >> 4;

    float acc[4][4];
#pragma unroll
    for (int i = 0; i < 4; i++)
#pragma unroll
        for (int j = 0; j < 4; j++) acc[i][j] = 0.f;

    for (int k0 = 0; k0 < 384; k0 += 32) {
        __syncthreads();
#pragma unroll
        for (int l = 0; l < 2; l++) {
            int idx = t * 2 + l;
            int r = idx >> 3, c4 = (idx & 7) * 4;
            float4 av = *(const float4*)(a + (size_t)(m0 + r) * 384 + k0 + c4);
            As[c4 + 0][r] = av.x;
            As[c4 + 1][r] = av.y;
            As[c4 + 2][r] = av.z;
            As[c4 + 3][r] = av.w;
        }
#pragma unroll
        for (int l = 0; l < 2; l++) {
            int idx = t * 2 + l;
            int r = idx >> 3, c4 = (idx & 7) * 4;
            float4 wv = *(const float4*)(w + (size_t)(c0 + r) * 384 + k0 + c4);
            Bs[c4 + 0][r] = wv.x;
            Bs[c4 + 1][r] = wv.y;
            Bs[c4 + 2][r] = wv.z;
            Bs[c4 + 3][r] = wv.w;
        }
        __syncthreads();
#pragma unroll
        for (int kk = 0; kk < 32; kk++) {
            float4 a4 = *(float4*)&As[kk][ty * 4];
            float4 b4 = *(float4*)&Bs[kk][tx * 4];
            float av[4] = {a4.x, a4.y, a4.z, a4.w};
            float bv[4] = {b4.x, b4.y, b4.z, b4.w};
#pragma unroll
            for (int i = 0; i < 4; i++)
#pragma unroll
                for (int j = 0; j < 4; j++) acc[i][j] += av[i] * bv[j];
        }
    }
    const int col = c0 + tx * 4;
    float4 bb = *(const float4*)(bias + col);
#pragma unroll
    for (int i = 0; i < 4; i++) {
        int row = m0 + ty * 4 + i;
        float4 o = {acc[i][0] + bb.x, acc[i][1] + bb.y,
                    acc[i][2] + bb.z, acc[i][3] + bb.w};
        *(float4*)(out + (size_t)row * 384 + col) = o;
    }
}

extern "C" void kernel_launch(void* const* d_in, const int* in_sizes, int n_in,
                              void* d_out, int out_size, void* d_ws, size_t ws_size,
                              hipStream_t stream) {
    const float* x     = (const float*)d_in[0];
    const float* w_qkv = (const float*)d_in[1];
    const float* w_out = (const float*)d_in[2];
    const float* b_out = (const float*)d_in[3];
    const float* tw    = (const float*)d_in[4];
    float* out = (float*)d_out;

    float* qw = (float*)d_ws;            // 48*1024*32 = 1572864 floats
    float* kw = qw + 1572864;
    float* vw = kw + 1572864;
    float* op = vw + 1572864;            // 4096*384  = 1572864 floats

    qkv_gemm<<<dim3(18, 64), 256, 0, stream>>>(x, w_qkv, qw, kw, vw);
    toep_attn<<<dim3(16, 48), 256, 0, stream>>>(qw, kw, vw, tw, op);
    out_gemm<<<dim3(6, 64), 256, 0, stream>>>(op, w_out, b_out, out);
}